// Round 4
// baseline (215.592 us; speedup 1.0000x reference)
//
#include <hip/hip_runtime.h>
#include <cstdint>

// ConvBnA int8 conv via i8 MFMA (exact: i32 accumulation).
// Pass 1a: weight int32 [co][ci][3][3] -> int8 [g][co][ci] (+ zero page)
// Pass 1b: x int32 NCHW -> int8 NHWC, register-only transpose
// Pass 2 : implicit GEMM, 8-phase-style schedule (T3+T4+T5):
//          128co x 128px tile, 512 thr / 8 waves (2x4), K-tile = 1 tap (128ci),
//          triple-buffered LDS (96KB), counted vmcnt(4) at tap boundaries,
//          [chunk][row] conflict-free LDS layout, per-phase
//          {ds_read || stage-issue -> barrier -> lgkm(0) -> setprio MFMA}.
// Output: harness reads integer outputs as int32 -> store int.

typedef __attribute__((ext_vector_type(4))) int i32x4;
typedef __attribute__((ext_vector_type(2))) int i32x2;

#define C_IN   128
#define HW2    3136      // 56*56
#define OUT_NSTRIDE 802816  // 256*3136

// workspace layout (bytes)
#define XQ_BYTES 12845056            // 100352 * 128 int8
#define WQ_OFF   XQ_BYTES
#define WQ_BYTES 294912              // 9*256*128 int8
#define ZP_OFF   (WQ_OFF + WQ_BYTES) // 256 zero bytes (16B-aligned)

__device__ __forceinline__ void gload_lds16(const void* g, void* l) {
  __builtin_amdgcn_global_load_lds(
      (const __attribute__((address_space(1))) void*)(uintptr_t)g,
      (__attribute__((address_space(3))) void*)(uint32_t)(uintptr_t)l,
      16, 0, 0);
}

// ---------------- pass 1a: weight -> int8 [g][co][ci] + zero page ----------------
__global__ void wxform(const int* __restrict__ w, char* __restrict__ wq,
                       int* __restrict__ zp) {
  int id = blockIdx.x * 256 + threadIdx.x;      // over 9*256*128 = 294912
  int ci = id & 127;
  int co = (id >> 7) & 255;
  int g  = id >> 15;                            // kh*3+kw
  wq[id] = (char)w[co * 1152 + ci * 9 + g];
  if (blockIdx.x == 0 && threadIdx.x < 64) zp[threadIdx.x] = 0;
}

// ---------------- pass 1b: x NCHW int32 -> NHWC int8, reg-only transpose ----------------
__global__ __launch_bounds__(256) void xform(const int* __restrict__ x,
                                             char* __restrict__ xq) {
  int bid = blockIdx.x;                 // 32n * 49hb = 1568 blocks
  int hb = bid % 49;
  int n  = bid / 49;
  int t  = threadIdx.x;
  int cig = t & 15;                     // ci group (8 ci each)
  int hw0 = (t >> 4) * 4;               // 4 pixels
  const int* src = x + n * (C_IN * HW2) + hb * 64 + hw0;
  i32x4 ld[8];
#pragma unroll
  for (int j = 0; j < 8; j++)
    ld[j] = *(const i32x4*)(src + (cig * 8 + j) * HW2);
  char* dst = xq + (size_t)(n * HW2 + hb * 64 + hw0) * 128 + cig * 8;
#pragma unroll
  for (int p = 0; p < 4; p++) {
    unsigned lo = (ld[0][p] & 255) | ((ld[1][p] & 255) << 8) |
                  ((ld[2][p] & 255) << 16) | ((unsigned)(ld[3][p] & 255) << 24);
    unsigned hi = (ld[4][p] & 255) | ((ld[5][p] & 255) << 8) |
                  ((ld[6][p] & 255) << 16) | ((unsigned)(ld[7][p] & 255) << 24);
    i32x2 v; v[0] = (int)lo; v[1] = (int)hi;
    *(i32x2*)(dst + p * 128) = v;
  }
}

// ---------------- pass 2: i8 MFMA implicit GEMM, fine-phase schedule ----------------
__global__ __launch_bounds__(512, 1) void conv_mfma(
    const char* __restrict__ xq, const char* __restrict__ wq,
    const char* __restrict__ zp,
    const int* __restrict__ nshift, const int* __restrict__ tbias,
    const int* __restrict__ aminp, const int* __restrict__ amaxp,
    int* __restrict__ out) {
  __shared__ char lds[98304];   // 3 tap-bufs x (A 16KB + B 16KB)
  // LDS layout per tile: [chunk c(8)][row r(128)] 16B units -> linear addr = (c*128+r)*16
  // ds_read: lanes 0..15 -> consecutive rows -> 256B contiguous: conflict-free.

  const int tid = threadIdx.x;
  const int bid = blockIdx.x;
  // XCD-aware bijective swizzle: 1568 = 8 * 196
  const int swz = (bid & 7) * 196 + (bid >> 3);
  const int bm = swz / 784;       // co half (0..1)
  const int pb = swz % 784;       // pixel block
  const int l   = tid & 63;
  const int wid = tid >> 6;
  const int wm = wid >> 2;        // 0..1 : co quarter within tile (64 rows)
  const int wn = wid & 3;         // 0..3 : px 32-slice

  // ---- staging geometry: slot s = tid + i*512; c = s>>7, r = s&127; dest = s*16 ----
  const int r_ = tid & 127;       // row (co for A / px for B), same for both loads
  const int c0 = tid >> 7;        // chunk 0..3 (second load: c0+4)
  const char* wsrcA = wq + (bm * 128 + r_) * 128;     // + g*32768 + c*16
  const int p = pb * 128 + r_;
  const int n_img = p / HW2;
  const int hw = p - n_img * HW2;
  const int ph = hw / 56, pw = hw - (hw / 56) * 56;
  const char* xsrc = xq + (size_t)p * 128;

  auto stageA = [&](int g, char* Ab) {
    const char* s = wsrcA + g * 32768;
    gload_lds16(s + c0 * 16,       Ab + (c0 * 128 + r_) * 16);
    gload_lds16(s + (c0 + 4) * 16, Ab + ((c0 + 4) * 128 + r_) * 16);
  };
  auto stageB = [&](int g, char* Bb) {
    const int g3 = g / 3;
    const int dh = g3 - 1, dw = g - g3 * 3 - 1;
    const bool valid = ((unsigned)(ph + dh) < 56u) && ((unsigned)(pw + dw) < 56u);
    const char* s = valid ? (xsrc + (dh * 56 + dw) * 128) : zp;
    gload_lds16(s + c0 * 16,       Bb + (c0 * 128 + r_) * 16);
    gload_lds16(s + (c0 + 4) * 16, Bb + ((c0 + 4) * 128 + r_) * 16);
  };

  i32x4 acc[4][2] = {};
  const int lrow16 = (l & 15) * 16;
  const int lch = l >> 4;          // 0..3 : k-chunk within K=64

  // prologue: taps 0,1 fully staged (8 loads/thread in flight)
  stageA(0, lds);            stageB(0, lds + 16384);
  stageA(1, lds + 32768);    stageB(1, lds + 32768 + 16384);

  int cur = 0;
#pragma unroll 1
  for (int t = 0; t < 9; ++t) {
    // tap-top: counted wait — tap t's 4 loads (oldest) done; tap t+1's stay in flight
    if (t < 8) { asm volatile("s_waitcnt vmcnt(4)" ::: "memory"); }
    else       { asm volatile("s_waitcnt vmcnt(0)" ::: "memory"); }
    __builtin_amdgcn_s_barrier();

    char* Ab = lds + cur * 32768;
    char* Bb = Ab + 16384;
    int nxt = cur + 2; if (nxt >= 3) nxt -= 3;
    char* An = lds + nxt * 32768;

#pragma unroll
    for (int kk = 0; kk < 2; ++kk) {
      i32x4 a[4], b[2];
      const int coff = (kk * 4 + lch) * 2048;
#pragma unroll
      for (int mi = 0; mi < 4; mi++)
        a[mi] = *(const i32x4*)(Ab + coff + wm * 1024 + mi * 256 + lrow16);
#pragma unroll
      for (int ni = 0; ni < 2; ni++)
        b[ni] = *(const i32x4*)(Bb + coff + wn * 512 + ni * 256 + lrow16);
      if (t < 7) {                       // stage tap t+2 into buf nxt, spread
        if (kk == 0) stageA(t + 2, An);
        else         stageB(t + 2, An + 16384);
      }
      __builtin_amdgcn_s_barrier();
      asm volatile("s_waitcnt lgkmcnt(0)" ::: "memory");
      __builtin_amdgcn_sched_barrier(0);               // rule 18
      __builtin_amdgcn_s_setprio(1);
#pragma unroll
      for (int mi = 0; mi < 4; mi++)
#pragma unroll
        for (int ni = 0; ni < 2; ni++)
          acc[mi][ni] = __builtin_amdgcn_mfma_i32_16x16x64_i8(
              a[mi], b[ni], acc[mi][ni], 0, 0, 0);
      __builtin_amdgcn_s_setprio(0);
      __builtin_amdgcn_sched_barrier(0);
      __builtin_amdgcn_s_barrier();
    }
    cur = cur + 1; if (cur == 3) cur = 0;
  }

  // ---- epilogue: +t, >> (-n), clamp, store int32 ----
  const int amin = aminp[0], amax = amaxp[0];
  int pbase[2];
#pragma unroll
  for (int ni = 0; ni < 2; ni++) {
    int pp = pb * 128 + wn * 32 + ni * 16 + (l & 15);
    int nn = pp / HW2;
    int hh = pp - nn * HW2;
    pbase[ni] = nn * OUT_NSTRIDE + hh;
  }
#pragma unroll
  for (int mi = 0; mi < 4; mi++) {
    int co0 = bm * 128 + wm * 64 + mi * 16 + ((l >> 4) << 2);
    const int4 t4 = *(const int4*)(tbias + co0);
    const int4 n4 = *(const int4*)(nshift + co0);
#pragma unroll
    for (int ni = 0; ni < 2; ni++) {
#pragma unroll
      for (int r = 0; r < 4; r++) {
        int tv = (r == 0) ? t4.x : (r == 1) ? t4.y : (r == 2) ? t4.z : t4.w;
        int nv = (r == 0) ? n4.x : (r == 1) ? n4.y : (r == 2) ? n4.z : n4.w;
        int v = acc[mi][ni][r] + tv;
        v = v >> (-nv);                       // arithmetic shift
        v = v < amin ? amin : (v > amax ? amax : v);
        out[pbase[ni] + (co0 + r) * HW2] = v;
      }
    }
  }
}

extern "C" void kernel_launch(void* const* d_in, const int* in_sizes, int n_in,
                              void* d_out, int out_size, void* d_ws, size_t ws_size,
                              hipStream_t stream) {
  const int* x      = (const int*)d_in[0];
  const int* w      = (const int*)d_in[1];
  const int* nshift = (const int*)d_in[2];
  const int* tbias  = (const int*)d_in[3];
  const int* aminp  = (const int*)d_in[4];
  const int* amaxp  = (const int*)d_in[5];
  int* out = (int*)d_out;

  char* xq = (char*)d_ws;
  char* wq = (char*)d_ws + WQ_OFF;
  char* zp = (char*)d_ws + ZP_OFF;

  hipLaunchKernelGGL(wxform, dim3(1152), dim3(256), 0, stream, w, wq, (int*)zp);
  hipLaunchKernelGGL(xform,  dim3(1568), dim3(256), 0, stream, x, xq);
  hipLaunchKernelGGL(conv_mfma, dim3(1568), dim3(512), 0, stream,
                     xq, wq, zp, nshift, tbias, aminp, amaxp, out);
}

// Round 5
// 209.522 us; speedup vs baseline: 1.0290x; 1.0290x over previous
//
#include <hip/hip_runtime.h>
#include <cstdint>

// ConvBnA int8 conv via i8 MFMA (exact: i32 accumulation).
// Pass 1a: weight int32 [co][ci][3][3] -> int8 [g][co][ci] (+ zero page)
// Pass 1b: x int32 NCHW -> int8 NHWC, register-only transpose
// Pass 2 : implicit GEMM, 128co x 128px tile, 256 thr / 4 waves (2x2),
//          BK=64 (half-tap), TRIPLE-buffered LDS (48KB -> 3 blocks/CU),
//          ONE raw s_barrier per K-step + counted vmcnt(4) (never drains
//          mid-loop), [chunk][row] conflict-free LDS, 16x16x64 i8 MFMA,
//          setprio around the 16-MFMA cluster.
// Output: harness reads integer outputs as int32 -> store int.

typedef __attribute__((ext_vector_type(4))) int i32x4;
typedef __attribute__((ext_vector_type(2))) int i32x2;

#define C_IN   128
#define HW2    3136      // 56*56
#define OUT_NSTRIDE 802816  // 256*3136

// workspace layout (bytes)
#define XQ_BYTES 12845056            // 100352 * 128 int8
#define WQ_OFF   XQ_BYTES
#define WQ_BYTES 294912              // 9*256*128 int8
#define ZP_OFF   (WQ_OFF + WQ_BYTES) // 256 zero bytes (16B-aligned)

__device__ __forceinline__ void gload_lds16(const void* g, void* l) {
  __builtin_amdgcn_global_load_lds(
      (const __attribute__((address_space(1))) void*)(uintptr_t)g,
      (__attribute__((address_space(3))) void*)(uint32_t)(uintptr_t)l,
      16, 0, 0);
}

// ---------------- pass 1a: weight -> int8 [g][co][ci] + zero page ----------------
__global__ void wxform(const int* __restrict__ w, char* __restrict__ wq,
                       int* __restrict__ zp) {
  int id = blockIdx.x * 256 + threadIdx.x;      // over 9*256*128 = 294912
  int ci = id & 127;
  int co = (id >> 7) & 255;
  int g  = id >> 15;                            // kh*3+kw
  wq[id] = (char)w[co * 1152 + ci * 9 + g];
  if (blockIdx.x == 0 && threadIdx.x < 64) zp[threadIdx.x] = 0;
}

// ---------------- pass 1b: x NCHW int32 -> NHWC int8, reg-only transpose ----------------
__global__ __launch_bounds__(256) void xform(const int* __restrict__ x,
                                             char* __restrict__ xq) {
  int bid = blockIdx.x;                 // 32n * 49hb = 1568 blocks
  int hb = bid % 49;
  int n  = bid / 49;
  int t  = threadIdx.x;
  int cig = t & 15;                     // ci group (8 ci each)
  int hw0 = (t >> 4) * 4;               // 4 pixels
  const int* src = x + n * (C_IN * HW2) + hb * 64 + hw0;
  i32x4 ld[8];
#pragma unroll
  for (int j = 0; j < 8; j++)
    ld[j] = *(const i32x4*)(src + (cig * 8 + j) * HW2);
  char* dst = xq + (size_t)(n * HW2 + hb * 64 + hw0) * 128 + cig * 8;
#pragma unroll
  for (int p = 0; p < 4; p++) {
    unsigned lo = (ld[0][p] & 255) | ((ld[1][p] & 255) << 8) |
                  ((ld[2][p] & 255) << 16) | ((unsigned)(ld[3][p] & 255) << 24);
    unsigned hi = (ld[4][p] & 255) | ((ld[5][p] & 255) << 8) |
                  ((ld[6][p] & 255) << 16) | ((unsigned)(ld[7][p] & 255) << 24);
    i32x2 v; v[0] = (int)lo; v[1] = (int)hi;
    *(i32x2*)(dst + p * 128) = v;
  }
}

// ---------------- pass 2: i8 MFMA implicit GEMM, 1-barrier/step ----------------
__global__ __launch_bounds__(256, 3) void conv_mfma(
    const char* __restrict__ xq, const char* __restrict__ wq,
    const char* __restrict__ zp,
    const int* __restrict__ nshift, const int* __restrict__ tbias,
    const int* __restrict__ aminp, const int* __restrict__ amaxp,
    int* __restrict__ out) {
  __shared__ char lds[49152];   // 3 bufs x (A 8KB + B 8KB)
  // per buf: [chunk c(4)][row r(128)] 16B units; addr = (c*128+r)*16.
  // ds_read_b128: lanes 0..15 consecutive rows -> 256B contiguous (0 conflicts, r4-verified)

  const int tid = threadIdx.x;
  const int bid = blockIdx.x;
  // XCD-aware bijective swizzle: 1568 = 8 * 196
  const int swz = (bid & 7) * 196 + (bid >> 3);
  const int bm = swz / 784;       // co half (0..1)
  const int pb = swz % 784;       // pixel block
  const int l   = tid & 63;
  const int wid = tid >> 6;
  const int wm = wid >> 1, wn = wid & 1;   // 2x2 waves, 64x64 tile each

  // ---- staging geometry: thread handles slots tid, tid+256 of 512 (16B each)
  const int r_ = tid & 127;       // row (co for A / px for B), same both chunks
  const int cA = tid >> 7;        // chunk 0..1 (second: +2)
  const char* wbase = wq + (bm * 128 + r_) * 128;   // + g*32768 + kh*64 + c*16
  const int p = pb * 128 + r_;
  const int n_img = p / HW2;
  const int hw = p - n_img * HW2;
  const int ph = hw / 56, pw = hw - ph * 56;
  const char* xbase = xq + (size_t)p * 128;

  auto stage = [&](int s, char* buf) {    // s = step index (g = s>>1, kh = s&1)
    const int g = s >> 1, kh = s & 1;
    char* Ab = buf;
    char* Bb = buf + 8192;
    const char* as = wbase + g * 32768 + kh * 64;
    gload_lds16(as + cA * 16,       Ab + (cA * 128 + r_) * 16);
    gload_lds16(as + (cA + 2) * 16, Ab + ((cA + 2) * 128 + r_) * 16);
    const int g3 = g / 3;
    const int dh = g3 - 1, dw = g - g3 * 3 - 1;
    const bool valid = ((unsigned)(ph + dh) < 56u) && ((unsigned)(pw + dw) < 56u);
    const char* bs = valid ? (xbase + (dh * 56 + dw) * 128 + kh * 64) : zp;
    gload_lds16(bs + cA * 16,       Bb + (cA * 128 + r_) * 16);
    gload_lds16(bs + (cA + 2) * 16, Bb + ((cA + 2) * 128 + r_) * 16);
  };

  i32x4 acc[4][4] = {};
  const int lr16 = (l & 15) * 16;
  const int lch  = l >> 4;               // k-chunk 0..3 (K=64 = 4 x 16B)

  // prologue: steps 0,1 staged (8 loads/thread in flight)
  stage(0, lds);
  stage(1, lds + 16384);

#pragma unroll 1
  for (int t = 0; t < 18; ++t) {
    // counted wait: step t's 4 loads done; step t+1's 4 stay in flight
    if (t < 17) { asm volatile("s_waitcnt vmcnt(4)" ::: "memory"); }
    else        { asm volatile("s_waitcnt vmcnt(0)" ::: "memory"); }
    __builtin_amdgcn_s_barrier();        // all waves: compute(t-1) done + step-t LDS visible
    __builtin_amdgcn_sched_barrier(0);   // no read hoisting above barrier
    const int cur = t % 3;
    char* Ab = lds + cur * 16384;
    char* Bb = Ab + 8192;
    if (t < 16) stage(t + 2, lds + ((t + 2) % 3) * 16384);  // overwrites buf of compute(t-1)
    i32x4 a[4], b[4];
#pragma unroll
    for (int mi = 0; mi < 4; mi++)
      a[mi] = *(const i32x4*)(Ab + (lch * 128 + wm * 64 + mi * 16) * 16 + lr16);
#pragma unroll
    for (int ni = 0; ni < 4; ni++)
      b[ni] = *(const i32x4*)(Bb + (lch * 128 + wn * 64 + ni * 16) * 16 + lr16);
    __builtin_amdgcn_s_setprio(1);
#pragma unroll
    for (int mi = 0; mi < 4; mi++)
#pragma unroll
      for (int ni = 0; ni < 4; ni++)
        acc[mi][ni] = __builtin_amdgcn_mfma_i32_16x16x64_i8(
            a[mi], b[ni], acc[mi][ni], 0, 0, 0);
    __builtin_amdgcn_s_setprio(0);
  }

  // ---- epilogue: +t, >> (-n), clamp, store int32 (r3-verified mapping) ----
  const int amin = aminp[0], amax = amaxp[0];
  int pbase[4];
#pragma unroll
  for (int ni = 0; ni < 4; ni++) {
    int pp = pb * 128 + wn * 64 + ni * 16 + (l & 15);
    int nn = pp / HW2;
    int hh = pp - nn * HW2;
    pbase[ni] = nn * OUT_NSTRIDE + hh;
  }
#pragma unroll
  for (int mi = 0; mi < 4; mi++) {
    int co0 = bm * 128 + wm * 64 + mi * 16 + (lch << 2);
    const int4 t4 = *(const int4*)(tbias + co0);
    const int4 n4 = *(const int4*)(nshift + co0);
#pragma unroll
    for (int ni = 0; ni < 4; ni++) {
#pragma unroll
      for (int r = 0; r < 4; r++) {
        int tv = (r == 0) ? t4.x : (r == 1) ? t4.y : (r == 2) ? t4.z : t4.w;
        int nv = (r == 0) ? n4.x : (r == 1) ? n4.y : (r == 2) ? n4.z : n4.w;
        int v = acc[mi][ni][r] + tv;
        v = v >> (-nv);                       // arithmetic shift
        v = v < amin ? amin : (v > amax ? amax : v);
        out[pbase[ni] + (co0 + r) * HW2] = v;
      }
    }
  }
}

extern "C" void kernel_launch(void* const* d_in, const int* in_sizes, int n_in,
                              void* d_out, int out_size, void* d_ws, size_t ws_size,
                              hipStream_t stream) {
  const int* x      = (const int*)d_in[0];
  const int* w      = (const int*)d_in[1];
  const int* nshift = (const int*)d_in[2];
  const int* tbias  = (const int*)d_in[3];
  const int* aminp  = (const int*)d_in[4];
  const int* amaxp  = (const int*)d_in[5];
  int* out = (int*)d_out;

  char* xq = (char*)d_ws;
  char* wq = (char*)d_ws + WQ_OFF;
  char* zp = (char*)d_ws + ZP_OFF;

  hipLaunchKernelGGL(wxform, dim3(1152), dim3(256), 0, stream, w, wq, (int*)zp);
  hipLaunchKernelGGL(xform,  dim3(1568), dim3(256), 0, stream, x, xq);
  hipLaunchKernelGGL(conv_mfma, dim3(1568), dim3(256), 0, stream,
                     xq, wq, zp, nshift, tbias, aminp, amaxp, out);
}